// Round 4
// baseline (3052.022 us; speedup 1.0000x reference)
//
#include <hip/hip_runtime.h>
#include <math.h>

#define HW 65536
#define C1F 1.0e-4f
#define C2F 9.0e-4f
#define STE 34                 // htE/htQ row stride in v2f (272B: rows advance 4 banks)
#define STP 36                 // htP row stride in floats (144B, matched R4's 0-conflict layout)

typedef float v2f __attribute__((ext_vector_type(2)));

__device__ __constant__ float G11[11] = {
  0.0010284f, 0.0075987f, 0.0360008f, 0.1093607f, 0.2130056f,
  0.2660118f, 0.2130056f, 0.1093607f, 0.0360008f, 0.0075987f, 0.0010284f
};

// ws layout: float accum[0..4] = {abs_dc, ssim, hdiff, vdiff, cos} (bytes 0..19);
//            unsigned mask count @24; unsigned ticket @32; hist (B*192 u32) @64.

__device__ __forceinline__ void cos_hist_px(float mv, float g0, float g1, float g2,
                                            float P0, float P1, float P2,
                                            float& cos_sum, unsigned& cnt,
                                            unsigned* lh)
{
  // bin = floor(g*64) clipped (algebraically equals the reference index chain)
  int i0 = min(max((int)(g0*64.f), 0), 63);
  int i1 = min(max((int)(g1*64.f), 0), 63);
  int i2 = min(max((int)(g2*64.f), 0), 63);
  atomicAdd(&lh[i0],     1u);
  atomicAdd(&lh[64+i1],  1u);
  atomicAdd(&lh[128+i2], 1u);

  float p0 = P0*mv, p1 = P1*mv, p2 = P2*mv;
  float np2 = p0*p0 + p1*p1 + p2*p2;
  float invp = __builtin_amdgcn_rsqf(fmaxf(np2, 1e-24f));   // 1/max(||p||,1e-12)
  float t0 = (g0*mv*2.f - 1.f)*mv;
  float t1 = (g1*mv*2.f - 1.f)*mv;
  float t2 = (g2*mv*2.f - 1.f)*mv;
  float t2n = t0*t0 + t1*t1 + t2*t2;
  float invt = __builtin_amdgcn_rsqf(fmaxf(t2n, 1e-16f));   // 1/max(||t||,1e-8)
  float dot = p0*t0 + p1*t1 + p2*t2;
  // q = p*invp has ||q|| == 1 whenever p != 0 (n1==1); p==0 gives dot==0 -> cos=1
  cos_sum += 1.f - dot * invp * invt;
  cnt += (mv != 0.f) ? 1u : 0u;
}

// Vertical 11-tap over NR output rows from the LDS-staged horizontal results.
template<int NR>
__device__ __forceinline__ void vconv(const v2f* htE, const v2f* htQ, const float* htP,
                                      int r0, int col, float& ssim_sum)
{
  v2f aE[NR], aQ[NR]; float aP[NR];
#pragma unroll
  for (int j = 0; j < NR; ++j) { aE[j] = (v2f){0,0}; aQ[j] = (v2f){0,0}; aP[j] = 0.f; }
#pragma unroll
  for (int k = 0; k < NR+10; ++k) {
    v2f vE = htE[(r0+k)*STE + col];
    v2f vQ = htQ[(r0+k)*STE + col];
    float vP = htP[(r0+k)*STP + col];
#pragma unroll
    for (int j = 0; j < NR; ++j) {
      int t = k - j;
      if (t >= 0 && t < 11) {
        float w = G11[t];
        aE[j] += w * vE;
        aQ[j] += w * vQ;
        aP[j] = fmaf(w, vP, aP[j]);
      }
    }
  }
#pragma unroll
  for (int j = 0; j < NR; ++j) {
    float mu1 = aE[j].x, mu2 = aE[j].y;
    float x11 = aQ[j].x, x22 = aQ[j].y, x12 = aP[j];
    float mu1s = mu1*mu1, mu2s = mu2*mu2, mu12 = mu1*mu2;
    float num = (2.f*mu12 + C1F) * (2.f*(x12 - mu12) + C2F);
    float den = (mu1s + mu2s + C1F) * ((x11 - mu1s) + (x22 - mu2s) + C2F);
    ssim_sum += num * __builtin_amdgcn_rcpf(den);
  }
}

// Heterogeneous fused grid: B*208 blocks = B*192 ssim-tile blocks + B*16 cos/hist
// blocks, interleaved (every 13th block is cos). Last-finished block (global
// ticket) performs the hist |.| reduction + final combine -- zero extra launches.
// __launch_bounds__(384, 4): 128-VGPR cap, spill-free precedent. (384,8) forced
// VGPR=32 + 340MB scratch spill (round 1) -- never again.
__global__ __launch_bounds__(384, 4)
void fused_kernel(const float* __restrict__ dz_g, const float* __restrict__ cw_g,
                  const float* __restrict__ mk_g,
                  const float* __restrict__ pr_g, const float* __restrict__ gt_g,
                  const float* __restrict__ nh,
                  float* __restrict__ accum, unsigned* __restrict__ mcount,
                  unsigned* __restrict__ hist, unsigned* __restrict__ ticket,
                  float* __restrict__ out, int B)
{
  // ssim path storage; cos path aliases htE (hist) and htQ (reductions).
  __shared__ __align__(16) v2f  htE[42*STE];   // 11424 B
  __shared__ __align__(16) v2f  htQ[42*STE];   // 11424 B
  __shared__ __align__(16) float htP[42*STP];  //  6048 B
  __shared__ float red[24];
  __shared__ unsigned lastflag;

  int tid = threadIdx.x;
  int gbid = blockIdx.x;
  int q13 = gbid / 13;
  int r13 = gbid % 13;

  if (r13 == 0) {
    // ================= cos / hist block (B*16 total) =================
    unsigned* lh = (unsigned*)htE;          // 192 u32
    float*    redf = (float*)htQ;           // idx 0..5
    unsigned* redi = (unsigned*)htQ + 8;    // idx 8..13

    for (int i = tid; i < 192; i += 384) lh[i] = 0u;
    __syncthreads();

    int cidx = q13;                 // 0..B*16-1
    int b = cidx >> 4;
    int chunk = cidx & 15;
    const float4* pv  = (const float4*)(pr_g + (size_t)b*3*HW);
    const float4* gv  = (const float4*)(gt_g + (size_t)b*3*HW);
    const float4* mv4 = (const float4*)(mk_g + (size_t)b*HW);
    int base4 = chunk*1024;

    float cos_sum = 0.f;
    unsigned cnt = 0u;
    for (int it = 0; it < 3; ++it) {
      int j = it*384 + tid;
      if (j < 1024) {
        int i4 = base4 + j;
        float4 M  = mv4[i4];
        float4 G0 = gv[i4], G1 = gv[16384 + i4], G2 = gv[2*16384 + i4];
        float4 P0 = pv[i4], P1 = pv[16384 + i4], P2 = pv[2*16384 + i4];
        cos_hist_px(M.x, G0.x, G1.x, G2.x, P0.x, P1.x, P2.x, cos_sum, cnt, lh);
        cos_hist_px(M.y, G0.y, G1.y, G2.y, P0.y, P1.y, P2.y, cos_sum, cnt, lh);
        cos_hist_px(M.z, G0.z, G1.z, G2.z, P0.z, P1.z, P2.z, cos_sum, cnt, lh);
        cos_hist_px(M.w, G0.w, G1.w, G2.w, P0.w, P1.w, P2.w, cos_sum, cnt, lh);
      }
    }

#pragma unroll
    for (int off = 32; off > 0; off >>= 1) {
      cos_sum += __shfl_down(cos_sum, off);
      cnt     += __shfl_down(cnt,     off);
    }
    if ((tid & 63) == 0) { redf[tid>>6] = cos_sum; redi[tid>>6] = cnt; }
    __syncthreads();
    if (tid == 0) {
      atomicAdd(&accum[4], redf[0]+redf[1]+redf[2]+redf[3]+redf[4]+redf[5]);
      atomicAdd(mcount, redi[0]+redi[1]+redi[2]+redi[3]+redi[4]+redi[5]);
    }
    for (int i = tid; i < 192; i += 384) {
      unsigned v = lh[i];
      if (v) atomicAdd(&hist[b*192 + i], v);
    }
  } else {
    // ================= ssim / tv block (B*192 total) =================
    int sidx = q13*12 + (r13 - 1);
    int tx = sidx & 7;
    int ty = (sidx >> 3) & 7;
    int plane = sidx >> 6;          // b*3 + c
    int b = plane / 3;

    const float* dz = dz_g + (size_t)plane * HW;
    const float* cw = cw_g + (size_t)plane * HW;
    const float* mk = mk_g + (size_t)b * HW;

    // Block-uniform interior predicate: tx in [1,6] -> fi0 in [6,57] (no col
    // clamp); ty in [1,6] -> gr in [27,228] (no row clamp, rowv==1).
    bool fastRC = (tx >= 1) & (tx <= 6) & (ty >= 1) & (ty <= 6);

    float abs_sum = 0.f, h_sum = 0.f, v_sum = 0.f, ssim_sum = 0.f;

    // ---- horizontal 11-tap directly from global (L1-served), 336 runs of 4 cols ----
    if (tid < 336) {
      int run = tid;
      int hr = run >> 3;                 // 0..41 (ht row)
      int jr = run & 7;                  // 0..7
      int gr = ty*32 - 5 + hr;           // global row, may be OOB
      int grc = min(max(gr, 0), 255);
      int cbase = tx*32 + 4*jr;          // output base col (0..252)
      int fi0 = (cbase >> 2) - 2;        // first float4 idx of 20-float window

      const float4* rdz = (const float4*)(dz + grc*256);
      const float4* rcw = (const float4*)(cw + grc*256);
      const float4* rmk = (const float4*)(mk + grc*256);

      v2f e2[14];                        // {d, c} masked, window idx 3..16
      if (fastRC) {
        // no clamps, no validity math, me == mq
#pragma unroll
        for (int qq = 0; qq < 5; ++qq) {
          float4 aq = rdz[fi0 + qq];
          float4 bq = rcw[fi0 + qq];
          float4 mq = rmk[fi0 + qq];
          float ae[4] = {aq.x, aq.y, aq.z, aq.w};
          float be[4] = {bq.x, bq.y, bq.z, bq.w};
          float me[4] = {mq.x, mq.y, mq.z, mq.w};
#pragma unroll
          for (int e = 0; e < 4; ++e) {
            int wi = 4*qq + e;
            if (wi >= 3 && wi <= 16) {
              v2f t; t.x = ae[e]*me[e]; t.y = be[e]*me[e];
              e2[wi-3] = t;
            }
          }
        }
      } else {
        float rowv = ((unsigned)gr < 256u) ? 1.f : 0.f;
#pragma unroll
        for (int qq = 0; qq < 5; ++qq) {
          int fi = fi0 + qq;
          int fic = min(max(fi, 0), 63);
          float4 aq = rdz[fic];
          float4 bq = rcw[fic];
          float4 mq = rmk[fic];
          float vf = (((unsigned)fi < 64u) ? 1.f : 0.f) * rowv;
          float ae[4] = {aq.x, aq.y, aq.z, aq.w};
          float be[4] = {bq.x, bq.y, bq.z, bq.w};
          float me[4] = {mq.x*vf, mq.y*vf, mq.z*vf, mq.w*vf};
#pragma unroll
          for (int e = 0; e < 4; ++e) {
            int wi = 4*qq + e;
            if (wi >= 3 && wi <= 16) {
              v2f t; t.x = ae[e]*me[e]; t.y = be[e]*me[e];
              e2[wi-3] = t;
            }
          }
        }
      }

      // products hoisted out of the tap loop
      v2f q2[14]; float dp[14];
#pragma unroll
      for (int i = 0; i < 14; ++i) {
        q2[i] = e2[i]*e2[i];             // {d*d, c*c} (v_pk_mul_f32)
        dp[i] = e2[i].x * e2[i].y;       // d*c
      }

      v2f aE[4] = {{0,0},{0,0},{0,0},{0,0}};   // {mu1, mu2}
      v2f aQ[4] = {{0,0},{0,0},{0,0},{0,0}};   // {s11, s22}
      float aP[4] = {0,0,0,0};                 // s12
#pragma unroll
      for (int k = 0; k < 11; ++k) {
        float w = G11[k];
#pragma unroll
        for (int j = 0; j < 4; ++j) {
          aE[j] += w * e2[j+k];          // 1 v_pk_fma_f32
          aQ[j] += w * q2[j+k];          // 1 v_pk_fma_f32
          aP[j] = fmaf(w, dp[j+k], aP[j]);
        }
      }
      int o = hr*STE + 4*jr;             // even -> 16B aligned
      *(float4*)&htE[o]   = make_float4(aE[0].x, aE[0].y, aE[1].x, aE[1].y);
      *(float4*)&htE[o+2] = make_float4(aE[2].x, aE[2].y, aE[3].x, aE[3].y);
      *(float4*)&htQ[o]   = make_float4(aQ[0].x, aQ[0].y, aQ[1].x, aQ[1].y);
      *(float4*)&htQ[o+2] = make_float4(aQ[2].x, aQ[2].y, aQ[3].x, aQ[3].y);
      *(float4*)&htP[hr*STP + 4*jr] = make_float4(aP[0], aP[1], aP[2], aP[3]);

      // fused terms on interior rows (hr in [5,36] <=> gr in tile rows, in-bounds)
      float itf = (hr >= 5 && hr <= 36) ? 1.f : 0.f;
      // L1 |d-c| on run cols (window 8..11 -> local 5..8)
      abs_sum += itf * (fabsf(e2[5].x-e2[5].y) + fabsf(e2[6].x-e2[6].y)
                      + fabsf(e2[7].x-e2[7].y) + fabsf(e2[8].x-e2[8].y));
      // h-TV: |d(col)-d(col+1)|, col<255 (only cbase+3==255 can fail)
      float h3 = (cbase + 3 < 255) ? 1.f : 0.f;
      h_sum += itf * (fabsf(e2[5].x-e2[6].x) + fabsf(e2[6].x-e2[7].x)
                    + fabsf(e2[7].x-e2[8].x) + h3*fabsf(e2[8].x-e2[9].x));
      // v-TV: |d(gr)-d(gr+1)|; gr2 clamped BOTH sides (gr can be -5)
      {
        int gr2 = min(max(gr + 1, 0), 255);
        float4 a2  = ((const float4*)(dz + gr2*256))[fi0 + 2];
        float4 m2q = ((const float4*)(mk + gr2*256))[fi0 + 2];
        float vtf = itf * ((gr < 255) ? 1.f : 0.f);
        v_sum += vtf * (fabsf(e2[5].x - a2.x*m2q.x) + fabsf(e2[6].x - a2.y*m2q.y)
                      + fabsf(e2[7].x - a2.z*m2q.z) + fabsf(e2[8].x - a2.w*m2q.w));
      }
    }
    __syncthreads();

    // ---- vertical 11-tap: 12 groups (8x3 rows + 4x2 rows) -> all 6 waves busy ----
    {
      int col = tid & 31;
      int g = tid >> 5;              // 0..11 (wave-uniform pairs: branch is uniform)
      if (g < 8) vconv<3>(htE, htQ, htP, 3*g,          col, ssim_sum);
      else       vconv<2>(htE, htQ, htP, 24 + 2*(g-8), col, ssim_sum);
    }

#pragma unroll
    for (int off = 32; off > 0; off >>= 1) {
      abs_sum  += __shfl_down(abs_sum,  off);
      ssim_sum += __shfl_down(ssim_sum, off);
      h_sum    += __shfl_down(h_sum,    off);
      v_sum    += __shfl_down(v_sum,    off);
    }
    if ((tid & 63) == 0) {
      int w = tid >> 6;
      red[w*4+0]=abs_sum; red[w*4+1]=ssim_sum; red[w*4+2]=h_sum; red[w*4+3]=v_sum;
    }
    __syncthreads();
    if (tid < 4) {
      float s = red[tid] + red[4+tid] + red[8+tid]
              + red[12+tid] + red[16+tid] + red[20+tid];
      atomicAdd(&accum[tid], s);
    }
  }

  // ================= last-block epilogue (ticket) =================
  __threadfence();
  if (tid == 0) {
    unsigned old = __hip_atomic_fetch_add(ticket, 1u, __ATOMIC_ACQ_REL,
                                          __HIP_MEMORY_SCOPE_AGENT);
    lastflag = (old == (unsigned)(gridDim.x - 1)) ? 1u : 0u;
  }
  __syncthreads();
  if (lastflag) {
    int n = B*192;
    float hs = 0.f;
    for (int i = tid; i < n; i += 384) {
      unsigned hv = __hip_atomic_load(&hist[i], __ATOMIC_RELAXED,
                                      __HIP_MEMORY_SCOPE_AGENT);
      hs += fabsf(nh[i] - (float)hv * (1.f/65536.f));
    }
#pragma unroll
    for (int off = 32; off > 0; off >>= 1) hs += __shfl_down(hs, off);
    if ((tid & 63) == 0) red[tid>>6] = hs;
    __syncthreads();
    if (tid == 0) {
      float hist_sum = red[0]+red[1]+red[2]+red[3]+red[4]+red[5];
      float a0 = __hip_atomic_load(&accum[0], __ATOMIC_RELAXED, __HIP_MEMORY_SCOPE_AGENT);
      float a1 = __hip_atomic_load(&accum[1], __ATOMIC_RELAXED, __HIP_MEMORY_SCOPE_AGENT);
      float a2 = __hip_atomic_load(&accum[2], __ATOMIC_RELAXED, __HIP_MEMORY_SCOPE_AGENT);
      float a3 = __hip_atomic_load(&accum[3], __ATOMIC_RELAXED, __HIP_MEMORY_SCOPE_AGENT);
      float a4 = __hip_atomic_load(&accum[4], __ATOMIC_RELAXED, __HIP_MEMORY_SCOPE_AGENT);
      unsigned mc = __hip_atomic_load(mcount, __ATOMIC_RELAXED, __HIP_MEMORY_SCOPE_AGENT);
      float Np = (float)B * 3.f * 65536.f;
      float L_dehaze = a0 / Np;
      float L_ssim = 1.f - a1 / Np;
      float L_tv = a2 / ((float)B*3.f*256.f*255.f)
                 + a3 / ((float)B*3.f*255.f*256.f);
      float L_hist = hs >= 0.f ? hist_sum / (float)n : 0.f;
      float M = (float)mc;
      float back = (float)B * 65536.f - M;
      float L_normal = (a4 - back) / M;
      out[0] = 10.f*L_dehaze + L_ssim + L_tv + L_hist + 100.f*L_normal;
    }
  }
}

extern "C" void kernel_launch(void* const* d_in, const int* in_sizes, int n_in,
                              void* d_out, int out_size, void* d_ws, size_t ws_size,
                              hipStream_t stream)
{
  const float* predict = (const float*)d_in[0];
  const float* gt      = (const float*)d_in[1];
  const float* dehaze  = (const float*)d_in[2];
  const float* cleanw  = (const float*)d_in[3];
  const float* nh      = (const float*)d_in[4];
  const float* mask    = (const float*)d_in[5];
  int B = in_sizes[0] / (3*HW);

  float* accum      = (float*)d_ws;
  unsigned* mcount  = (unsigned*)((char*)d_ws + 24);
  unsigned* ticket  = (unsigned*)((char*)d_ws + 32);
  unsigned* hist    = (unsigned*)((char*)d_ws + 64);

  hipMemsetAsync(d_ws, 0, 64 + (size_t)B*192*4, stream);

  // B*208 blocks = B*192 ssim (r13!=0) + B*16 cos/hist (r13==0), interleaved.
  fused_kernel<<<B*208, 384, 0, stream>>>(dehaze, cleanw, mask, predict, gt, nh,
                                          accum, mcount, hist, ticket,
                                          (float*)d_out, B);
}

// Round 5
// 278.251 us; speedup vs baseline: 10.9686x; 10.9686x over previous
//
#include <hip/hip_runtime.h>
#include <math.h>

#define HW 65536
#define C1F 1.0e-4f
#define C2F 9.0e-4f
#define STE 34                 // htE/htQ row stride in v2f (272B: rows advance 4 banks)
#define STP 36                 // htP row stride in floats (144B, 0-conflict layout)
#define STS 49                 // sDC row stride in v2f (odd -> 2 words mod 32: minimal
                               // 4-way conflict for the b64 window reads; 8B-aligned only,
                               // so all sDC accesses are v2f/b64, never float4)

typedef float v2f __attribute__((ext_vector_type(2)));

__device__ __constant__ float G11[11] = {
  0.0010284f, 0.0075987f, 0.0360008f, 0.1093607f, 0.2130056f,
  0.2660118f, 0.2130056f, 0.1093607f, 0.0360008f, 0.0075987f, 0.0010284f
};

// ws layout: float accum[64] spread over 8 slots of 8 @0 (use [s*8+0..4] =
//   {abs_dc, ssim, hdiff, vdiff, cos}); unsigned mcount @256; float habs @288;
//   hist (B*192 u32) @320.
// ROUND-4 LESSON (global): per-block __threadfence() (agent-scope release) on
// gfx950 forces an L2 writeback per block -> 15x regression (202->2950us,
// VALUBusy 33->2%). Keep grid-wide reductions in a separate tiny kernel.

__device__ __forceinline__ void cos_hist_px(float mv, float g0, float g1, float g2,
                                            float P0, float P1, float P2,
                                            float& cos_sum, unsigned& cnt,
                                            unsigned* lh)
{
  // bin = floor(g*64) clipped (algebraically equals the reference index chain)
  int i0 = min(max((int)(g0*64.f), 0), 63);
  int i1 = min(max((int)(g1*64.f), 0), 63);
  int i2 = min(max((int)(g2*64.f), 0), 63);
  atomicAdd(&lh[i0],     1u);
  atomicAdd(&lh[64+i1],  1u);
  atomicAdd(&lh[128+i2], 1u);

  float p0 = P0*mv, p1 = P1*mv, p2 = P2*mv;
  float np2 = p0*p0 + p1*p1 + p2*p2;
  float invp = __builtin_amdgcn_rsqf(fmaxf(np2, 1e-24f));   // 1/max(||p||,1e-12)
  float t0 = (g0*mv*2.f - 1.f)*mv;
  float t1 = (g1*mv*2.f - 1.f)*mv;
  float t2 = (g2*mv*2.f - 1.f)*mv;
  float t2n = t0*t0 + t1*t1 + t2*t2;
  float invt = __builtin_amdgcn_rsqf(fmaxf(t2n, 1e-16f));   // 1/max(||t||,1e-8)
  float dot = p0*t0 + p1*t1 + p2*t2;
  cos_sum += 1.f - dot * invp * invt;
  cnt += (mv != 0.f) ? 1u : 0u;
}

// Vertical 11-tap over NR output rows from the LDS-staged horizontal results.
template<int NR>
__device__ __forceinline__ void vconv(const v2f* htE, const v2f* htQ, const float* htP,
                                      int r0, int col, float& ssim_sum)
{
  v2f aE[NR], aQ[NR]; float aP[NR];
#pragma unroll
  for (int j = 0; j < NR; ++j) { aE[j] = (v2f){0,0}; aQ[j] = (v2f){0,0}; aP[j] = 0.f; }
#pragma unroll
  for (int k = 0; k < NR+10; ++k) {
    v2f vE = htE[(r0+k)*STE + col];
    v2f vQ = htQ[(r0+k)*STE + col];
    float vP = htP[(r0+k)*STP + col];
#pragma unroll
    for (int j = 0; j < NR; ++j) {
      int t = k - j;
      if (t >= 0 && t < 11) {
        float w = G11[t];
        aE[j] += w * vE;
        aQ[j] += w * vQ;
        aP[j] = fmaf(w, vP, aP[j]);
      }
    }
  }
#pragma unroll
  for (int j = 0; j < NR; ++j) {
    float mu1 = aE[j].x, mu2 = aE[j].y;
    float x11 = aQ[j].x, x22 = aQ[j].y, x12 = aP[j];
    float mu1s = mu1*mu1, mu2s = mu2*mu2, mu12 = mu1*mu2;
    float num = (2.f*mu12 + C1F) * (2.f*(x12 - mu12) + C2F);
    float den = (mu1s + mu2s + C1F) * ((x11 - mu1s) + (x22 - mu2s) + C2F);
    ssim_sum += num * __builtin_amdgcn_rcpf(den);
  }
}

// Heterogeneous fused grid: B*208 blocks = B*192 ssim-tile blocks + B*16 cos/hist
// blocks, interleaved (every 13th block is cos).
// ssim path round 5: stage {d,c}={dz*mk,cw*mk} ONCE into LDS (1512 coalesced
// float4 loads/block vs 6384 window-redundant ones), then h-conv/v-TV read LDS.
__global__ __launch_bounds__(384, 4)
void fused_kernel(const float* __restrict__ dz_g, const float* __restrict__ cw_g,
                  const float* __restrict__ mk_g,
                  const float* __restrict__ pr_g, const float* __restrict__ gt_g,
                  float* __restrict__ accum, unsigned* __restrict__ mcount,
                  unsigned* __restrict__ hist)
{
  __shared__ __align__(16) v2f  sDC[42*STS];   // 16464 B  {d, c} staged window
  __shared__ __align__(16) v2f  htE[42*STE];   // 11424 B  {mu1_h, mu2_h}
  __shared__ __align__(16) v2f  htQ[42*STE];   // 11424 B  {s11_h, s22_h}
  __shared__ __align__(16) float htP[42*STP];  //  6048 B  s12_h
  __shared__ float red[24];

  int tid = threadIdx.x;
  int gbid = blockIdx.x;
  int q13 = gbid / 13;
  int r13 = gbid % 13;
  int slot = (gbid & 7) * 8;      // spread accum atomics over 8 cache lines

  if (r13 == 0) {
    // ================= cos / hist block (B*16 total) =================
    unsigned* lh = (unsigned*)htE;          // 192 u32
    float*    redf = (float*)htQ;           // idx 0..5
    unsigned* redi = (unsigned*)htQ + 8;    // idx 8..13

    for (int i = tid; i < 192; i += 384) lh[i] = 0u;
    __syncthreads();

    int cidx = q13;                 // 0..B*16-1
    int b = cidx >> 4;
    int chunk = cidx & 15;
    const float4* pv  = (const float4*)(pr_g + (size_t)b*3*HW);
    const float4* gv  = (const float4*)(gt_g + (size_t)b*3*HW);
    const float4* mv4 = (const float4*)(mk_g + (size_t)b*HW);
    int base4 = chunk*1024;

    float cos_sum = 0.f;
    unsigned cnt = 0u;
    for (int it = 0; it < 3; ++it) {
      int j = it*384 + tid;
      if (j < 1024) {
        int i4 = base4 + j;
        float4 M  = mv4[i4];
        float4 G0 = gv[i4], G1 = gv[16384 + i4], G2 = gv[2*16384 + i4];
        float4 P0 = pv[i4], P1 = pv[16384 + i4], P2 = pv[2*16384 + i4];
        cos_hist_px(M.x, G0.x, G1.x, G2.x, P0.x, P1.x, P2.x, cos_sum, cnt, lh);
        cos_hist_px(M.y, G0.y, G1.y, G2.y, P0.y, P1.y, P2.y, cos_sum, cnt, lh);
        cos_hist_px(M.z, G0.z, G1.z, G2.z, P0.z, P1.z, P2.z, cos_sum, cnt, lh);
        cos_hist_px(M.w, G0.w, G1.w, G2.w, P0.w, P1.w, P2.w, cos_sum, cnt, lh);
      }
    }

#pragma unroll
    for (int off = 32; off > 0; off >>= 1) {
      cos_sum += __shfl_down(cos_sum, off);
      cnt     += __shfl_down(cnt,     off);
    }
    if ((tid & 63) == 0) { redf[tid>>6] = cos_sum; redi[tid>>6] = cnt; }
    __syncthreads();
    if (tid == 0) {
      atomicAdd(&accum[slot + 4], redf[0]+redf[1]+redf[2]+redf[3]+redf[4]+redf[5]);
      atomicAdd(mcount, redi[0]+redi[1]+redi[2]+redi[3]+redi[4]+redi[5]);
    }
    for (int i = tid; i < 192; i += 384) {
      unsigned v = lh[i];
      if (v) atomicAdd(&hist[b*192 + i], v);
    }
    return;
  }

  // ================= ssim / tv block (B*192 total) =================
  int sidx = q13*12 + (r13 - 1);
  int tx = sidx & 7;
  int ty = (sidx >> 3) & 7;
  int plane = sidx >> 6;          // b*3 + c
  int b = plane / 3;

  const float* dz = dz_g + (size_t)plane * HW;
  const float* cw = cw_g + (size_t)plane * HW;
  const float* mk = mk_g + (size_t)b * HW;

  const int R0 = ty*32 - 5;       // first window row (may be <0)
  const int F0 = 8*tx - 2;        // first window float4 col (may be <0)

  // ---- stage masked {d,c} window: 42 rows x 12 float4, coalesced, once ----
  for (int t = tid; t < 504; t += 384) {
    int row = t / 12;
    int f   = t - row*12;
    int gr = R0 + row;
    int fi = F0 + f;
    int grc = min(max(gr, 0), 255);
    int fic = min(max(fi, 0), 63);
    float v = (((unsigned)gr < 256u) && ((unsigned)fi < 64u)) ? 1.f : 0.f;
    float4 a = ((const float4*)(dz + grc*256))[fic];
    float4 c = ((const float4*)(cw + grc*256))[fic];
    float4 m = ((const float4*)(mk + grc*256))[fic];
    float m0 = m.x*v, m1 = m.y*v, m2 = m.z*v, m3 = m.w*v;
    int o = row*STS + 4*f;
    sDC[o]   = (v2f){a.x*m0, c.x*m0};     // b64 stores: STS odd -> only 8B-aligned
    sDC[o+1] = (v2f){a.y*m1, c.y*m1};
    sDC[o+2] = (v2f){a.z*m2, c.z*m2};
    sDC[o+3] = (v2f){a.w*m3, c.w*m3};
  }
  __syncthreads();

  float abs_sum = 0.f, h_sum = 0.f, v_sum = 0.f, ssim_sum = 0.f;

  // ---- horizontal 11-tap from LDS, 336 runs of 4 cols ----
  if (tid < 336) {
    int hr = tid >> 3;                 // 0..41
    int jr = tid & 7;                  // 0..7
    int cbase = tx*32 + 4*jr;          // output base col
    int lbase = hr*STS + 4*jr;         // sDC row base + local col offset

    v2f e2[14];                        // {d, c}, window local cols 4jr+3 .. 4jr+16
#pragma unroll
    for (int i = 0; i < 14; ++i) e2[i] = sDC[lbase + 3 + i];

    v2f q2[14]; float dp[14];
#pragma unroll
    for (int i = 0; i < 14; ++i) {
      q2[i] = e2[i]*e2[i];             // {d*d, c*c}
      dp[i] = e2[i].x * e2[i].y;       // d*c
    }

    v2f aE[4] = {{0,0},{0,0},{0,0},{0,0}};
    v2f aQ[4] = {{0,0},{0,0},{0,0},{0,0}};
    float aP[4] = {0,0,0,0};
#pragma unroll
    for (int k = 0; k < 11; ++k) {
      float w = G11[k];
#pragma unroll
      for (int j = 0; j < 4; ++j) {
        aE[j] += w * e2[j+k];
        aQ[j] += w * q2[j+k];
        aP[j] = fmaf(w, dp[j+k], aP[j]);
      }
    }
    int o = hr*STE + 4*jr;             // even -> 16B aligned
    *(float4*)&htE[o]   = make_float4(aE[0].x, aE[0].y, aE[1].x, aE[1].y);
    *(float4*)&htE[o+2] = make_float4(aE[2].x, aE[2].y, aE[3].x, aE[3].y);
    *(float4*)&htQ[o]   = make_float4(aQ[0].x, aQ[0].y, aQ[1].x, aQ[1].y);
    *(float4*)&htQ[o+2] = make_float4(aQ[2].x, aQ[2].y, aQ[3].x, aQ[3].y);
    *(float4*)&htP[hr*STP + 4*jr] = make_float4(aP[0], aP[1], aP[2], aP[3]);

    // fused terms on interior rows (hr in [5,36] <=> gr in tile rows, in-bounds)
    float itf = (hr >= 5 && hr <= 36) ? 1.f : 0.f;
    // L1 |d-c| on run cols (local e2 idx 5..8 == cols cbase..cbase+3)
    abs_sum += itf * (fabsf(e2[5].x-e2[5].y) + fabsf(e2[6].x-e2[6].y)
                    + fabsf(e2[7].x-e2[7].y) + fabsf(e2[8].x-e2[8].y));
    // h-TV: |d(col)-d(col+1)|, col<255 (only cbase+3==255 can fail)
    float h3 = (cbase + 3 < 255) ? 1.f : 0.f;
    h_sum += itf * (fabsf(e2[5].x-e2[6].x) + fabsf(e2[6].x-e2[7].x)
                  + fabsf(e2[7].x-e2[8].x) + h3*fabsf(e2[8].x-e2[9].x));
    // v-TV: |d(gr)-d(gr+1)|; next row's d is in sDC (hr+1 <= 37 when itf!=0)
    {
      int hr2 = min(hr + 1, 41);
      int l2 = hr2*STS + 4*jr + 8;     // local col of cbase
      float vtf = itf * ((R0 + hr < 255) ? 1.f : 0.f);
      v_sum += vtf * (fabsf(e2[5].x - sDC[l2].x)   + fabsf(e2[6].x - sDC[l2+1].x)
                    + fabsf(e2[7].x - sDC[l2+2].x) + fabsf(e2[8].x - sDC[l2+3].x));
    }
  }
  __syncthreads();

  // ---- vertical 11-tap: 12 groups (8x3 rows + 4x2 rows), all 6 waves busy ----
  {
    int col = tid & 31;
    int g = tid >> 5;              // 0..11 (wave-uniform pairs)
    if (g < 8) vconv<3>(htE, htQ, htP, 3*g,          col, ssim_sum);
    else       vconv<2>(htE, htQ, htP, 24 + 2*(g-8), col, ssim_sum);
  }

#pragma unroll
  for (int off = 32; off > 0; off >>= 1) {
    abs_sum  += __shfl_down(abs_sum,  off);
    ssim_sum += __shfl_down(ssim_sum, off);
    h_sum    += __shfl_down(h_sum,    off);
    v_sum    += __shfl_down(v_sum,    off);
  }
  if ((tid & 63) == 0) {
    int w = tid >> 6;
    red[w*4+0]=abs_sum; red[w*4+1]=ssim_sum; red[w*4+2]=h_sum; red[w*4+3]=v_sum;
  }
  __syncthreads();
  if (tid < 4) {
    float s = red[tid] + red[4+tid] + red[8+tid]
            + red[12+tid] + red[16+tid] + red[20+tid];
    atomicAdd(&accum[slot + tid], s);
  }
}

// Parallel |nh - hist/65536| reduction across 48 blocks.
__global__ __launch_bounds__(256)
void hist_reduce_kernel(const float* __restrict__ nh, const unsigned* __restrict__ hist,
                        float* __restrict__ habs, int n)
{
  int i = blockIdx.x*256 + threadIdx.x;
  float hs = 0.f;
  if (i < n) hs = fabsf(nh[i] - (float)hist[i] * (1.f/65536.f));
#pragma unroll
  for (int off = 32; off > 0; off >>= 1) hs += __shfl_down(hs, off);
  if ((threadIdx.x & 63) == 0) atomicAdd(habs, hs);
}

__global__ void final_combine(const float* __restrict__ accum,
                              const unsigned* __restrict__ mcount,
                              const float* __restrict__ habs,
                              float* __restrict__ out, int B)
{
  if (threadIdx.x == 0) {
    float a[5] = {0,0,0,0,0};
    for (int s = 0; s < 8; ++s)
      for (int k = 0; k < 5; ++k) a[k] += accum[s*8 + k];
    float Np = (float)B * 3.f * 65536.f;
    float L_dehaze = a[0] / Np;
    float L_ssim = 1.f - a[1] / Np;
    float L_tv = a[2] / ((float)B*3.f*256.f*255.f)
               + a[3] / ((float)B*3.f*255.f*256.f);
    float L_hist = habs[0] / (float)(B*192);
    float M = (float)(*mcount);
    float back = (float)B * 65536.f - M;
    float L_normal = (a[4] - back) / M;
    out[0] = 10.f*L_dehaze + L_ssim + L_tv + L_hist + 100.f*L_normal;
  }
}

extern "C" void kernel_launch(void* const* d_in, const int* in_sizes, int n_in,
                              void* d_out, int out_size, void* d_ws, size_t ws_size,
                              hipStream_t stream)
{
  const float* predict = (const float*)d_in[0];
  const float* gt      = (const float*)d_in[1];
  const float* dehaze  = (const float*)d_in[2];
  const float* cleanw  = (const float*)d_in[3];
  const float* nh      = (const float*)d_in[4];
  const float* mask    = (const float*)d_in[5];
  int B = in_sizes[0] / (3*HW);

  float* accum      = (float*)d_ws;                        // 64 floats (8 slots)
  unsigned* mcount  = (unsigned*)((char*)d_ws + 256);
  float* habs       = (float*)((char*)d_ws + 288);
  unsigned* hist    = (unsigned*)((char*)d_ws + 320);

  hipMemsetAsync(d_ws, 0, 320 + (size_t)B*192*4, stream);

  // B*208 blocks = B*192 ssim (r13!=0) + B*16 cos/hist (r13==0), interleaved.
  fused_kernel<<<B*208, 384, 0, stream>>>(dehaze, cleanw, mask, predict, gt,
                                          accum, mcount, hist);
  int n = B*192;
  hist_reduce_kernel<<<(n+255)/256, 256, 0, stream>>>(nh, hist, habs, n);
  final_combine<<<1, 64, 0, stream>>>(accum, mcount, habs, (float*)d_out, B);
}

// Round 6
// 252.116 us; speedup vs baseline: 12.1056x; 1.1037x over previous
//
#include <hip/hip_runtime.h>
#include <math.h>

#define HW 65536
#define C1F 1.0e-4f
#define C2F 9.0e-4f
#define STE 34                 // htE/htQ row stride in v2f (272B: rows advance 4 banks)
#define STP 36                 // htP row stride in floats (144B, 0-conflict layout)
#define STS 49                 // sDC row stride in v2f (odd -> good bank spread for b64)

typedef float v2f __attribute__((ext_vector_type(2)));

__device__ __constant__ float G11[11] = {
  0.0010284f, 0.0075987f, 0.0360008f, 0.1093607f, 0.2130056f,
  0.2660118f, 0.2130056f, 0.1093607f, 0.0360008f, 0.0075987f, 0.0010284f
};

// ws layout: float accum[64] spread over 8 slots of 8 @0 (use [s*8+0..4] =
//   {abs_dc, ssim, hdiff, vdiff, cos}); unsigned mcount @256; float habs @288;
//   hist (B*192 u32) @320.
// ROUND-4 LESSON (global): per-block __threadfence() (agent-scope release) on
// gfx950 forces an L2 writeback per block -> 15x regression. Keep grid-wide
// reductions in a separate tiny kernel.
// ROUND-6: sDC and htE/htQ have disjoint lifetimes -> union overlay. LDS
// 45568 -> ~29184 B restores 5 blocks/CU (30-wave cap). htP's union offset
// (22848) is beyond sDC's 16464 B extent, so htP writes stay in the h-phase;
// only htE/htQ writes are deferred past a barrier (16 VGPRs live).

union __align__(16) ShMem {
  v2f sDC[42*STS];                      // 16464 B  {d, c} staged window
  struct {
    v2f E[42*STE];                      // 11424 B  {mu1_h, mu2_h}
    v2f Q[42*STE];                      // 11424 B  {s11_h, s22_h}  (ends 22848)
    float P[42*STP];                    //  6048 B  s12_h (22848..28896: no sDC alias)
  } ht;
  unsigned lh[192];                     // cos-path histogram
};

__device__ __forceinline__ void cos_hist_px(float mv, float g0, float g1, float g2,
                                            float P0, float P1, float P2,
                                            float& cos_sum, unsigned& cnt,
                                            unsigned* lh)
{
  // bin = floor(g*64) clipped (algebraically equals the reference index chain)
  int i0 = min(max((int)(g0*64.f), 0), 63);
  int i1 = min(max((int)(g1*64.f), 0), 63);
  int i2 = min(max((int)(g2*64.f), 0), 63);
  atomicAdd(&lh[i0],     1u);
  atomicAdd(&lh[64+i1],  1u);
  atomicAdd(&lh[128+i2], 1u);

  float p0 = P0*mv, p1 = P1*mv, p2 = P2*mv;
  float np2 = p0*p0 + p1*p1 + p2*p2;
  float invp = __builtin_amdgcn_rsqf(fmaxf(np2, 1e-24f));   // 1/max(||p||,1e-12)
  float t0 = (g0*mv*2.f - 1.f)*mv;
  float t1 = (g1*mv*2.f - 1.f)*mv;
  float t2 = (g2*mv*2.f - 1.f)*mv;
  float t2n = t0*t0 + t1*t1 + t2*t2;
  float invt = __builtin_amdgcn_rsqf(fmaxf(t2n, 1e-16f));   // 1/max(||t||,1e-8)
  float dot = p0*t0 + p1*t1 + p2*t2;
  cos_sum += 1.f - dot * invp * invt;
  cnt += (mv != 0.f) ? 1u : 0u;
}

// Vertical 11-tap over NR output rows from the LDS-staged horizontal results.
template<int NR>
__device__ __forceinline__ void vconv(const v2f* htE, const v2f* htQ, const float* htP,
                                      int r0, int col, float& ssim_sum)
{
  v2f aE[NR], aQ[NR]; float aP[NR];
#pragma unroll
  for (int j = 0; j < NR; ++j) { aE[j] = (v2f){0,0}; aQ[j] = (v2f){0,0}; aP[j] = 0.f; }
#pragma unroll
  for (int k = 0; k < NR+10; ++k) {
    v2f vE = htE[(r0+k)*STE + col];
    v2f vQ = htQ[(r0+k)*STE + col];
    float vP = htP[(r0+k)*STP + col];
#pragma unroll
    for (int j = 0; j < NR; ++j) {
      int t = k - j;
      if (t >= 0 && t < 11) {
        float w = G11[t];
        aE[j] += w * vE;
        aQ[j] += w * vQ;
        aP[j] = fmaf(w, vP, aP[j]);
      }
    }
  }
#pragma unroll
  for (int j = 0; j < NR; ++j) {
    float mu1 = aE[j].x, mu2 = aE[j].y;
    float x11 = aQ[j].x, x22 = aQ[j].y, x12 = aP[j];
    float mu1s = mu1*mu1, mu2s = mu2*mu2, mu12 = mu1*mu2;
    float num = (2.f*mu12 + C1F) * (2.f*(x12 - mu12) + C2F);
    float den = (mu1s + mu2s + C1F) * ((x11 - mu1s) + (x22 - mu2s) + C2F);
    ssim_sum += num * __builtin_amdgcn_rcpf(den);
  }
}

// Heterogeneous fused grid: B*208 blocks = B*192 ssim-tile blocks + B*16 cos/hist
// blocks, interleaved (every 13th block is cos).
__global__ __launch_bounds__(384, 4)
void fused_kernel(const float* __restrict__ dz_g, const float* __restrict__ cw_g,
                  const float* __restrict__ mk_g,
                  const float* __restrict__ pr_g, const float* __restrict__ gt_g,
                  float* __restrict__ accum, unsigned* __restrict__ mcount,
                  unsigned* __restrict__ hist)
{
  __shared__ ShMem sh;                  // 28896 B (union)
  __shared__ float red[24];
  __shared__ float redf[6];
  __shared__ unsigned redi[6];

  int tid = threadIdx.x;
  int gbid = blockIdx.x;
  int q13 = gbid / 13;
  int r13 = gbid % 13;
  int slot = (gbid & 7) * 8;      // spread accum atomics over 8 cache lines

  if (r13 == 0) {
    // ================= cos / hist block (B*16 total) =================
    unsigned* lh = sh.lh;

    for (int i = tid; i < 192; i += 384) lh[i] = 0u;
    __syncthreads();

    int cidx = q13;                 // 0..B*16-1
    int b = cidx >> 4;
    int chunk = cidx & 15;
    const float4* pv  = (const float4*)(pr_g + (size_t)b*3*HW);
    const float4* gv  = (const float4*)(gt_g + (size_t)b*3*HW);
    const float4* mv4 = (const float4*)(mk_g + (size_t)b*HW);
    int base4 = chunk*1024;

    float cos_sum = 0.f;
    unsigned cnt = 0u;
    for (int it = 0; it < 3; ++it) {
      int j = it*384 + tid;
      if (j < 1024) {
        int i4 = base4 + j;
        float4 M  = mv4[i4];
        float4 G0 = gv[i4], G1 = gv[16384 + i4], G2 = gv[2*16384 + i4];
        float4 P0 = pv[i4], P1 = pv[16384 + i4], P2 = pv[2*16384 + i4];
        cos_hist_px(M.x, G0.x, G1.x, G2.x, P0.x, P1.x, P2.x, cos_sum, cnt, lh);
        cos_hist_px(M.y, G0.y, G1.y, G2.y, P0.y, P1.y, P2.y, cos_sum, cnt, lh);
        cos_hist_px(M.z, G0.z, G1.z, G2.z, P0.z, P1.z, P2.z, cos_sum, cnt, lh);
        cos_hist_px(M.w, G0.w, G1.w, G2.w, P0.w, P1.w, P2.w, cos_sum, cnt, lh);
      }
    }

#pragma unroll
    for (int off = 32; off > 0; off >>= 1) {
      cos_sum += __shfl_down(cos_sum, off);
      cnt     += __shfl_down(cnt,     off);
    }
    if ((tid & 63) == 0) { redf[tid>>6] = cos_sum; redi[tid>>6] = cnt; }
    __syncthreads();
    if (tid == 0) {
      atomicAdd(&accum[slot + 4], redf[0]+redf[1]+redf[2]+redf[3]+redf[4]+redf[5]);
      atomicAdd(mcount, redi[0]+redi[1]+redi[2]+redi[3]+redi[4]+redi[5]);
    }
    for (int i = tid; i < 192; i += 384) {
      unsigned v = lh[i];
      if (v) atomicAdd(&hist[b*192 + i], v);
    }
    return;
  }

  // ================= ssim / tv block (B*192 total) =================
  int sidx = q13*12 + (r13 - 1);
  int tx = sidx & 7;
  int ty = (sidx >> 3) & 7;
  int plane = sidx >> 6;          // b*3 + c
  int b = plane / 3;

  const float* dz = dz_g + (size_t)plane * HW;
  const float* cw = cw_g + (size_t)plane * HW;
  const float* mk = mk_g + (size_t)b * HW;

  const int R0 = ty*32 - 5;       // first window row (may be <0)
  const int F0 = 8*tx - 2;        // first window float4 col (may be <0)

  // ---- stage masked {d,c} window: 42 rows x 12 float4, coalesced, once ----
  for (int t = tid; t < 504; t += 384) {
    int row = t / 12;
    int f   = t - row*12;
    int gr = R0 + row;
    int fi = F0 + f;
    int grc = min(max(gr, 0), 255);
    int fic = min(max(fi, 0), 63);
    float v = (((unsigned)gr < 256u) && ((unsigned)fi < 64u)) ? 1.f : 0.f;
    float4 a = ((const float4*)(dz + grc*256))[fic];
    float4 c = ((const float4*)(cw + grc*256))[fic];
    float4 m = ((const float4*)(mk + grc*256))[fic];
    float m0 = m.x*v, m1 = m.y*v, m2 = m.z*v, m3 = m.w*v;
    int o = row*STS + 4*f;
    sh.sDC[o]   = (v2f){a.x*m0, c.x*m0};   // b64 stores: STS odd -> 8B-aligned only
    sh.sDC[o+1] = (v2f){a.y*m1, c.y*m1};
    sh.sDC[o+2] = (v2f){a.z*m2, c.z*m2};
    sh.sDC[o+3] = (v2f){a.w*m3, c.w*m3};
  }
  __syncthreads();

  float abs_sum = 0.f, h_sum = 0.f, v_sum = 0.f, ssim_sum = 0.f;
  bool act = (tid < 336);
  v2f aE[4] = {{0,0},{0,0},{0,0},{0,0}};   // live across the overlay barrier
  v2f aQ[4] = {{0,0},{0,0},{0,0},{0,0}};
  int oEQ = 0, oP = 0;

  // ---- horizontal 11-tap from LDS, 336 runs of 4 cols; results to regs ----
  if (act) {
    int hr = tid >> 3;                 // 0..41
    int jr = tid & 7;                  // 0..7
    int cbase = tx*32 + 4*jr;          // output base col
    int lbase = hr*STS + 4*jr;         // sDC row base + local col offset
    oEQ = hr*STE + 4*jr;
    oP  = hr*STP + 4*jr;

    v2f e2[14];                        // {d, c}, window local cols 4jr+3 .. 4jr+16
#pragma unroll
    for (int i = 0; i < 14; ++i) e2[i] = sh.sDC[lbase + 3 + i];

    v2f q2[14]; float dp[14];
#pragma unroll
    for (int i = 0; i < 14; ++i) {
      q2[i] = e2[i]*e2[i];             // {d*d, c*c}
      dp[i] = e2[i].x * e2[i].y;       // d*c
    }

    float aP[4] = {0,0,0,0};
#pragma unroll
    for (int k = 0; k < 11; ++k) {
      float w = G11[k];
#pragma unroll
      for (int j = 0; j < 4; ++j) {
        aE[j] += w * e2[j+k];
        aQ[j] += w * q2[j+k];
        aP[j] = fmaf(w, dp[j+k], aP[j]);
      }
    }
    // htP region (union offset 22848+) does not alias sDC (<16464): write now.
    *(float4*)&sh.ht.P[oP] = make_float4(aP[0], aP[1], aP[2], aP[3]);

    // fused terms on interior rows (hr in [5,36] <=> gr in tile rows, in-bounds)
    float itf = (hr >= 5 && hr <= 36) ? 1.f : 0.f;
    // L1 |d-c| on run cols (local e2 idx 5..8 == cols cbase..cbase+3)
    abs_sum += itf * (fabsf(e2[5].x-e2[5].y) + fabsf(e2[6].x-e2[6].y)
                    + fabsf(e2[7].x-e2[7].y) + fabsf(e2[8].x-e2[8].y));
    // h-TV: |d(col)-d(col+1)|, col<255 (only cbase+3==255 can fail)
    float h3 = (cbase + 3 < 255) ? 1.f : 0.f;
    h_sum += itf * (fabsf(e2[5].x-e2[6].x) + fabsf(e2[6].x-e2[7].x)
                  + fabsf(e2[7].x-e2[8].x) + h3*fabsf(e2[8].x-e2[9].x));
    // v-TV: |d(gr)-d(gr+1)|; next row's d is in sDC (hr+1 <= 37 when itf!=0)
    {
      int hr2 = min(hr + 1, 41);
      int l2 = hr2*STS + 4*jr + 8;     // local col of cbase
      float vtf = itf * ((R0 + hr < 255) ? 1.f : 0.f);
      v_sum += vtf * (fabsf(e2[5].x - sh.sDC[l2].x)   + fabsf(e2[6].x - sh.sDC[l2+1].x)
                    + fabsf(e2[7].x - sh.sDC[l2+2].x) + fabsf(e2[8].x - sh.sDC[l2+3].x));
    }
  }
  __syncthreads();          // all sDC reads done -> safe to overlay E/Q

  if (act) {
    *(float4*)&sh.ht.E[oEQ]   = make_float4(aE[0].x, aE[0].y, aE[1].x, aE[1].y);
    *(float4*)&sh.ht.E[oEQ+2] = make_float4(aE[2].x, aE[2].y, aE[3].x, aE[3].y);
    *(float4*)&sh.ht.Q[oEQ]   = make_float4(aQ[0].x, aQ[0].y, aQ[1].x, aQ[1].y);
    *(float4*)&sh.ht.Q[oEQ+2] = make_float4(aQ[2].x, aQ[2].y, aQ[3].x, aQ[3].y);
  }
  __syncthreads();

  // ---- vertical 11-tap: 12 groups (8x3 rows + 4x2 rows), all 6 waves busy ----
  {
    int col = tid & 31;
    int g = tid >> 5;              // 0..11 (wave-uniform pairs)
    if (g < 8) vconv<3>(sh.ht.E, sh.ht.Q, sh.ht.P, 3*g,          col, ssim_sum);
    else       vconv<2>(sh.ht.E, sh.ht.Q, sh.ht.P, 24 + 2*(g-8), col, ssim_sum);
  }

#pragma unroll
  for (int off = 32; off > 0; off >>= 1) {
    abs_sum  += __shfl_down(abs_sum,  off);
    ssim_sum += __shfl_down(ssim_sum, off);
    h_sum    += __shfl_down(h_sum,    off);
    v_sum    += __shfl_down(v_sum,    off);
  }
  if ((tid & 63) == 0) {
    int w = tid >> 6;
    red[w*4+0]=abs_sum; red[w*4+1]=ssim_sum; red[w*4+2]=h_sum; red[w*4+3]=v_sum;
  }
  __syncthreads();
  if (tid < 4) {
    float s = red[tid] + red[4+tid] + red[8+tid]
            + red[12+tid] + red[16+tid] + red[20+tid];
    atomicAdd(&accum[slot + tid], s);
  }
}

// Parallel |nh - hist/65536| reduction across 48 blocks.
__global__ __launch_bounds__(256)
void hist_reduce_kernel(const float* __restrict__ nh, const unsigned* __restrict__ hist,
                        float* __restrict__ habs, int n)
{
  int i = blockIdx.x*256 + threadIdx.x;
  float hs = 0.f;
  if (i < n) hs = fabsf(nh[i] - (float)hist[i] * (1.f/65536.f));
#pragma unroll
  for (int off = 32; off > 0; off >>= 1) hs += __shfl_down(hs, off);
  if ((threadIdx.x & 63) == 0) atomicAdd(habs, hs);
}

__global__ void final_combine(const float* __restrict__ accum,
                              const unsigned* __restrict__ mcount,
                              const float* __restrict__ habs,
                              float* __restrict__ out, int B)
{
  if (threadIdx.x == 0) {
    float a[5] = {0,0,0,0,0};
    for (int s = 0; s < 8; ++s)
      for (int k = 0; k < 5; ++k) a[k] += accum[s*8 + k];
    float Np = (float)B * 3.f * 65536.f;
    float L_dehaze = a[0] / Np;
    float L_ssim = 1.f - a[1] / Np;
    float L_tv = a[2] / ((float)B*3.f*256.f*255.f)
               + a[3] / ((float)B*3.f*255.f*256.f);
    float L_hist = habs[0] / (float)(B*192);
    float M = (float)(*mcount);
    float back = (float)B * 65536.f - M;
    float L_normal = (a[4] - back) / M;
    out[0] = 10.f*L_dehaze + L_ssim + L_tv + L_hist + 100.f*L_normal;
  }
}

extern "C" void kernel_launch(void* const* d_in, const int* in_sizes, int n_in,
                              void* d_out, int out_size, void* d_ws, size_t ws_size,
                              hipStream_t stream)
{
  const float* predict = (const float*)d_in[0];
  const float* gt      = (const float*)d_in[1];
  const float* dehaze  = (const float*)d_in[2];
  const float* cleanw  = (const float*)d_in[3];
  const float* nh      = (const float*)d_in[4];
  const float* mask    = (const float*)d_in[5];
  int B = in_sizes[0] / (3*HW);

  float* accum      = (float*)d_ws;                        // 64 floats (8 slots)
  unsigned* mcount  = (unsigned*)((char*)d_ws + 256);
  float* habs       = (float*)((char*)d_ws + 288);
  unsigned* hist    = (unsigned*)((char*)d_ws + 320);

  hipMemsetAsync(d_ws, 0, 320 + (size_t)B*192*4, stream);

  // B*208 blocks = B*192 ssim (r13!=0) + B*16 cos/hist (r13==0), interleaved.
  fused_kernel<<<B*208, 384, 0, stream>>>(dehaze, cleanw, mask, predict, gt,
                                          accum, mcount, hist);
  int n = B*192;
  hist_reduce_kernel<<<(n+255)/256, 256, 0, stream>>>(nh, hist, habs, n);
  final_combine<<<1, 64, 0, stream>>>(accum, mcount, habs, (float*)d_out, B);
}